// Round 3
// baseline (396.808 us; speedup 1.0000x reference)
//
#include <hip/hip_runtime.h>
#include <math.h>
#include <float.h>
#include <limits.h>

#define NB1 8192    // sample histogram bins: float bits >> 19 (sign+exp+4 mantissa)
#define NB2 4096    // fine linear histogram bins over the band
#define VEC 2       // float4 per thread in main kernel (8 elements)

// loss = max(x,0) - x*t + log1p(exp(-|x|)) >= 0 ; p = sigmoid(x)
__device__ __forceinline__ void elem_f(float x, float t, float& l, float& p) {
    float e = __expf(-fabsf(x));
    l = fmaxf(x, 0.f) - x * t + __logf(1.f + e);
    float r = __builtin_amdgcn_rcpf(1.f + e);
    p = (x >= 0.f) ? r : e * r;
}

// ---------- k0: 1/16 chunked sample -> coarse bit-histogram ----------
// sample index i -> float4 index (i>>6)*1024 + (i&63): contiguous 64-float4
// (4 KB) chunks, spaced 16 chunks apart. Coalesced wave loads.
__global__ __launch_bounds__(256) void sample_kernel(
    const float4* __restrict__ x4, const float4* __restrict__ t4,
    unsigned* __restrict__ H1, int n4)
{
    __shared__ unsigned lh[NB1];   // 32 KB
    for (int i = threadIdx.x; i < NB1; i += 256) lh[i] = 0u;
    __syncthreads();
    int tid = blockIdx.x * 256 + threadIdx.x;
    int stride = gridDim.x * 256;
    int S4 = n4 >> 4;              // number of sampled float4 pairs
    for (int i = tid; i < S4; i += stride) {
        int f4 = ((i >> 6) << 10) + (i & 63);
        if (f4 >= n4) continue;
        float4 xv = x4[f4];
        float4 tv = t4[f4];
        float xs[4] = {xv.x, xv.y, xv.z, xv.w};
        float ts[4] = {tv.x, tv.y, tv.z, tv.w};
        #pragma unroll
        for (int c = 0; c < 4; ++c) {
            float l, p;
            elem_f(xs[c], ts[c], l, p);
            atomicAdd(&lh[__float_as_uint(l) >> 19], 1u);
        }
    }
    __syncthreads();
    for (int i = threadIdx.x; i < NB1; i += 256) {
        unsigned c = lh[i];
        if (c) atomicAdd(&H1[i], c);
    }
}

// ---------- k1: pick value band [vlo, vhi) containing the kth value ----------
__global__ __launch_bounds__(64) void band_kernel(
    const unsigned* __restrict__ H1, float* __restrict__ band,
    long long ks, long long M)
{
    int lane = threadIdx.x;
    int base = lane << 7;          // 128 bins per lane
    unsigned long long chunk = 0;
    for (int j = 0; j < 128; ++j) chunk += H1[base + j];
    unsigned long long s = chunk;  // inclusive suffix-scan across lanes
    #pragma unroll
    for (int off = 1; off < 64; off <<= 1) {
        unsigned long long v = __shfl_down(s, off);
        if (lane + off < 64) s += v;
    }
    unsigned long long above = s - chunk;   // strictly above my chunk

    int my_bhi = INT_MAX, my_blo = -1;
    unsigned long long c = above;           // samples strictly above bin b
    for (int j = 127; j >= 0; --j) {
        unsigned h = H1[base + j];
        if ((long long)(c + h) < ks - M) my_bhi = base + j;
        if ((long long)c > ks + M && my_blo < 0) my_blo = base + j;
        c += h;
    }
    #pragma unroll
    for (int off = 32; off; off >>= 1) {
        int a = __shfl_down(my_bhi, off); my_bhi = min(my_bhi, a);
        int b = __shfl_down(my_blo, off); my_blo = max(my_blo, b);
    }
    if (lane == 0) {
        int bhi = (my_bhi == INT_MAX) ? (NB1 - 1) : my_bhi;
        int blo = my_blo;                   // may be -1
        float vhi = __uint_as_float((unsigned)bhi << 19);
        float vlo = (blo < 0) ? 0.f : __uint_as_float((unsigned)(blo + 1) << 19);
        if (!(vlo < vhi)) vlo = 0.f;
        band[0] = vlo;
        band[1] = vhi;
    }
}

__device__ __forceinline__ void process4(
    float4 xv, float4 tv, float vlo, float vhi, float scale,
    float& sp, float& spt, float& st, float& sgt, unsigned& cnt,
    unsigned* __restrict__ hist2)
{
    float xs[4] = {xv.x, xv.y, xv.z, xv.w};
    float ts[4] = {tv.x, tv.y, tv.z, tv.w};
    #pragma unroll
    for (int c = 0; c < 4; ++c) {
        float l, p;
        elem_f(xs[c], ts[c], l, p);
        sp += p; spt += p * ts[c]; st += ts[c];
        if (l >= vhi) { cnt++; sgt += l; }
        else if (l >= vlo) {
            int b = min((int)((l - vlo) * scale), NB2 - 1);
            atomicAdd(&hist2[b], 1u);
        }
    }
}

// ---------- k2: single full pass ----------
__global__ __launch_bounds__(256, 8) void main_kernel(
    const float4* __restrict__ x4, const float4* __restrict__ t4,
    const float* __restrict__ band, unsigned* __restrict__ hist2,
    double* __restrict__ sums, unsigned long long* __restrict__ cntg,
    const float* __restrict__ xg, const float* __restrict__ tg,
    int n, int n4)
{
    float vlo = band[0], vhi = band[1];
    float scale = (float)NB2 / (vhi - vlo);

    int base = blockIdx.x * (256 * VEC) + threadIdx.x;
    float sp = 0.f, spt = 0.f, st = 0.f, sgt = 0.f;
    unsigned cnt = 0;

    bool full = (blockIdx.x + 1) * (256 * VEC) <= n4;   // block-uniform
    if (full) {
        float4 xv[VEC], tv[VEC];
        #pragma unroll
        for (int j = 0; j < VEC; ++j) {      // all loads issued before any use
            xv[j] = x4[base + j * 256];
            tv[j] = t4[base + j * 256];
        }
        #pragma unroll
        for (int j = 0; j < VEC; ++j)
            process4(xv[j], tv[j], vlo, vhi, scale, sp, spt, st, sgt, cnt, hist2);
    } else {
        for (int j = 0; j < VEC; ++j) {
            int idx = base + j * 256;
            if (idx < n4)
                process4(x4[idx], t4[idx], vlo, vhi, scale, sp, spt, st, sgt, cnt, hist2);
        }
        // scalar tail (n % 4) on the last block's first threads
        int tail0 = n4 << 2;
        if (blockIdx.x == gridDim.x - 1 && threadIdx.x < (n - tail0)) {
            float x = xg[tail0 + threadIdx.x], t = tg[tail0 + threadIdx.x];
            float l, p;
            elem_f(x, t, l, p);
            sp += p; spt += p * t; st += t;
            if (l >= vhi) { cnt++; sgt += l; }
            else if (l >= vlo) {
                int b = min((int)((l - vlo) * scale), NB2 - 1);
                atomicAdd(&hist2[b], 1u);
            }
        }
    }

    // wave -> block -> one set of global atomics per block
    #pragma unroll
    for (int off = 32; off; off >>= 1) {
        sp  += __shfl_down(sp,  off);
        spt += __shfl_down(spt, off);
        st  += __shfl_down(st,  off);
        sgt += __shfl_down(sgt, off);
        cnt += __shfl_down(cnt, off);
    }
    __shared__ float    rs[4][4];
    __shared__ unsigned rc[4];
    int w = threadIdx.x >> 6;
    if ((threadIdx.x & 63) == 0) {
        rs[w][0] = sp; rs[w][1] = spt; rs[w][2] = st; rs[w][3] = sgt; rc[w] = cnt;
    }
    __syncthreads();
    if (threadIdx.x == 0) {
        double a0 = 0, a1 = 0, a2 = 0, a3 = 0;
        unsigned long long c = 0;
        for (int i = 0; i < 4; ++i) {
            a0 += rs[i][0]; a1 += rs[i][1]; a2 += rs[i][2]; a3 += rs[i][3]; c += rc[i];
        }
        atomicAdd(&sums[0], a0);
        atomicAdd(&sums[1], a1);
        atomicAdd(&sums[2], a2);
        atomicAdd(&sums[3], a3);
        atomicAdd(cntg, c);
    }
}

// ---------- k3: resolve threshold bin, emit scalar ----------
__global__ __launch_bounds__(64) void final_kernel(
    const unsigned* __restrict__ hist2, const float* __restrict__ band,
    const double* __restrict__ sums, const unsigned long long* __restrict__ cntg,
    float* __restrict__ out, long long k)
{
    int lane = threadIdx.x;
    double vlo = (double)band[0], vhi = (double)band[1];
    double binw = (vhi - vlo) / NB2;
    long long k2 = k - (long long)cntg[0];

    int base = lane << 6;                   // 64 bins per lane
    unsigned long long cchunk = 0;
    double wchunk = 0.0;
    for (int j = 0; j < 64; ++j) {
        unsigned h = hist2[base + j];
        cchunk += h;
        wchunk += (double)h * (vlo + (base + j + 0.5) * binw);
    }
    unsigned long long cs = cchunk;
    double wsum = wchunk;
    #pragma unroll
    for (int off = 1; off < 64; off <<= 1) {
        unsigned long long cv = __shfl_down(cs, off);
        double wv = __shfl_down(wsum, off);
        if (lane + off < 64) { cs += cv; wsum += wv; }
    }
    unsigned long long total = __shfl(cs, 0);
    double wtotal = __shfl(wsum, 0);

    double I = sums[1], U = sums[0] + sums[2];
    double dice_part = 0.5 * (1.0 - (2.0 * I + 1e-6) / (U + 1e-6));

    if (k2 <= 0) {
        if (lane == 0) out[0] = (float)(sums[3] / (double)k + dice_part);
        return;
    }
    if ((unsigned long long)k2 > total) {
        if (lane == 0) {
            double sum_top = sums[3] + wtotal + (double)(k2 - (long long)total) * vlo;
            out[0] = (float)(sum_top / (double)k + dice_part);
        }
        return;
    }
    unsigned long long c = cs - cchunk;
    double w = wsum - wchunk;
    for (int j = 63; j >= 0; --j) {
        unsigned h = hist2[base + j];
        double val = vlo + (base + j + 0.5) * binw;
        if (c < (unsigned long long)k2 && (unsigned long long)k2 <= c + h) {
            double sum_top = sums[3] + w + (double)((long long)k2 - (long long)c) * val;
            out[0] = (float)(sum_top / (double)k + dice_part);
        }
        c += h;
        w += (double)h * val;
    }
}

extern "C" void kernel_launch(void* const* d_in, const int* in_sizes, int n_in,
                              void* d_out, int out_size, void* d_ws, size_t ws_size,
                              hipStream_t stream)
{
    const float* x = (const float*)d_in[0];
    const float* t = (const float*)d_in[1];
    float* out = (float*)d_out;
    int n = in_sizes[0];
    int n4 = n >> 2;
    long long k = (long long)((double)n * 0.2);   // Python int() truncation
    if (k < 1) k = 1;

    long long S = (long long)(n4 >> 4) * 4;       // sampled element count
    long long ks = (long long)((double)k * (double)S / (double)n);
    long long M = 4096;                           // ~14 sigma sample-rank margin

    unsigned char* ws = (unsigned char*)d_ws;
    unsigned* H1    = (unsigned*)(ws);                        // 32 KB
    unsigned* hist2 = (unsigned*)(ws + 32768);                // 16 KB
    double*   sums  = (double*)(ws + 32768 + 16384);          // 4 doubles
    unsigned long long* cntg = (unsigned long long*)(ws + 32768 + 16384 + 32);
    float*    band  = (float*)(ws + 32768 + 16384 + 48);      // vlo, vhi

    hipMemsetAsync(d_ws, 0, 32768 + 16384 + 64, stream);

    sample_kernel<<<512, 256, 0, stream>>>((const float4*)x, (const float4*)t, H1, n4);
    band_kernel<<<1, 64, 0, stream>>>(H1, band, ks, M);
    int grid = (n4 + 256 * VEC - 1) / (256 * VEC);
    main_kernel<<<grid, 256, 0, stream>>>((const float4*)x, (const float4*)t,
                                          band, hist2, sums, cntg, x, t, n, n4);
    final_kernel<<<1, 64, 0, stream>>>(hist2, band, sums, cntg, out, k);
}

// Round 4
// 138.487 us; speedup vs baseline: 2.8653x; 2.8653x over previous
//
#include <hip/hip_runtime.h>
#include <math.h>
#include <limits.h>

#define NB1 8192    // sample histogram bins: float bits >> 19 (sign+exp+4 mantissa)
#define NB2 4096    // fine linear histogram bins over the band
#define VEC 4       // float4 per array per thread in main kernel (16 elements)

// loss = max(x,0) - x*t + log1p(exp(-|x|)) >= 0 ; p = sigmoid(x)
__device__ __forceinline__ void elem_f(float x, float t, float& l, float& p) {
    float e = __expf(-fabsf(x));
    l = fmaxf(x, 0.f) - x * t + __logf(1.f + e);
    float r = __builtin_amdgcn_rcpf(1.f + e);
    p = (x >= 0.f) ? r : e * r;
}

// ---------- k0: 1/16 chunked sample -> coarse bit-histogram ----------
__global__ __launch_bounds__(256) void sample_kernel(
    const float4* __restrict__ x4, const float4* __restrict__ t4,
    unsigned* __restrict__ H1, int n4)
{
    __shared__ unsigned lh[NB1];   // 32 KB
    for (int i = threadIdx.x; i < NB1; i += 256) lh[i] = 0u;
    __syncthreads();
    int tid = blockIdx.x * 256 + threadIdx.x;
    int stride = gridDim.x * 256;
    int S4 = n4 >> 4;              // sampled float4 pairs
    for (int i = tid; i < S4; i += stride) {
        int f4 = ((i >> 6) << 10) + (i & 63);   // contiguous 4KB chunks, 16x spaced
        if (f4 >= n4) continue;
        float4 xv = x4[f4];
        float4 tv = t4[f4];
        float xs[4] = {xv.x, xv.y, xv.z, xv.w};
        float ts[4] = {tv.x, tv.y, tv.z, tv.w};
        #pragma unroll
        for (int c = 0; c < 4; ++c) {
            float l, p;
            elem_f(xs[c], ts[c], l, p);
            atomicAdd(&lh[__float_as_uint(l) >> 19], 1u);
        }
    }
    __syncthreads();
    for (int i = threadIdx.x; i < NB1; i += 256) {
        unsigned c = lh[i];
        if (c) atomicAdd(&H1[i], c);
    }
}

// ---------- k1: pick value band [vlo, vhi) containing the kth value ----------
__global__ __launch_bounds__(256) void band_kernel(
    const unsigned* __restrict__ H1, float* __restrict__ band,
    long long ks, long long M)
{
    __shared__ unsigned lh[NB1];   // 32 KB
    const uint4* hv = (const uint4*)H1;
    uint4* lv = (uint4*)lh;
    for (int i = threadIdx.x; i < NB1 / 4; i += 256) lv[i] = hv[i];
    __syncthreads();
    if (threadIdx.x >= 64) return;

    int lane = threadIdx.x;
    int base = lane << 7;          // 128 bins per lane
    unsigned long long chunk = 0;
    for (int j = 0; j < 128; ++j) chunk += lh[base + j];
    unsigned long long s = chunk;  // inclusive suffix-scan across lanes
    #pragma unroll
    for (int off = 1; off < 64; off <<= 1) {
        unsigned long long v = __shfl_down(s, off);
        if (lane + off < 64) s += v;
    }
    unsigned long long above = s - chunk;

    int my_bhi = INT_MAX, my_blo = -1;
    unsigned long long c = above;
    for (int j = 127; j >= 0; --j) {
        unsigned h = lh[base + j];
        if ((long long)(c + h) < ks - M) my_bhi = base + j;
        if ((long long)c > ks + M && my_blo < 0) my_blo = base + j;
        c += h;
    }
    #pragma unroll
    for (int off = 32; off; off >>= 1) {
        int a = __shfl_down(my_bhi, off); my_bhi = min(my_bhi, a);
        int b = __shfl_down(my_blo, off); my_blo = max(my_blo, b);
    }
    if (lane == 0) {
        int bhi = (my_bhi == INT_MAX) ? (NB1 - 1) : my_bhi;
        int blo = my_blo;
        float vhi = __uint_as_float((unsigned)bhi << 19);
        float vlo = (blo < 0) ? 0.f : __uint_as_float((unsigned)(blo + 1) << 19);
        if (!(vlo < vhi)) vlo = 0.f;
        band[0] = vlo;
        band[1] = vhi;
    }
}

__device__ __forceinline__ void process4(
    float4 xv, float4 tv, float vlo, float vhi, float scale,
    float& sp, float& spt, float& st, float& sgt, unsigned& cnt,
    unsigned* __restrict__ hist2)
{
    float xs[4] = {xv.x, xv.y, xv.z, xv.w};
    float ts[4] = {tv.x, tv.y, tv.z, tv.w};
    #pragma unroll
    for (int c = 0; c < 4; ++c) {
        float l, p;
        elem_f(xs[c], ts[c], l, p);
        sp += p; spt += p * ts[c]; st += ts[c];
        if (l >= vhi) { cnt++; sgt += l; }
        else if (l >= vlo) {
            int b = min((int)((l - vlo) * scale), NB2 - 1);
            atomicAdd(&hist2[b], 1u);
        }
    }
}

// ---------- k2: single full pass; per-block partials to private slots ----------
__global__ __launch_bounds__(256, 8) void main_kernel(
    const float4* __restrict__ x4, const float4* __restrict__ t4,
    const float* __restrict__ band, unsigned* __restrict__ hist2,
    float* __restrict__ q0, float* __restrict__ q1,
    float* __restrict__ q2, float* __restrict__ q3, unsigned* __restrict__ qc,
    const float* __restrict__ xg, const float* __restrict__ tg,
    int n, int n4)
{
    float vlo = band[0], vhi = band[1];
    float scale = (float)NB2 / (vhi - vlo);

    int base = blockIdx.x * (256 * VEC) + threadIdx.x;
    float sp = 0.f, spt = 0.f, st = 0.f, sgt = 0.f;
    unsigned cnt = 0;

    bool full = (blockIdx.x + 1) * (256 * VEC) <= n4;   // block-uniform
    if (full) {
        float4 xv[VEC], tv[VEC];
        #pragma unroll
        for (int j = 0; j < VEC; ++j) xv[j] = x4[base + j * 256];
        #pragma unroll
        for (int j = 0; j < VEC; ++j) tv[j] = t4[base + j * 256];
        #pragma unroll
        for (int j = 0; j < VEC; ++j)
            process4(xv[j], tv[j], vlo, vhi, scale, sp, spt, st, sgt, cnt, hist2);
    } else {
        for (int j = 0; j < VEC; ++j) {
            int idx = base + j * 256;
            if (idx < n4)
                process4(x4[idx], t4[idx], vlo, vhi, scale, sp, spt, st, sgt, cnt, hist2);
        }
    }
    // scalar tail (n % 4) on block 0
    int tail0 = n4 << 2;
    if (blockIdx.x == 0 && threadIdx.x < (n - tail0)) {
        float x = xg[tail0 + threadIdx.x], t = tg[tail0 + threadIdx.x];
        float l, p;
        elem_f(x, t, l, p);
        sp += p; spt += p * t; st += t;
        if (l >= vhi) { cnt++; sgt += l; }
        else if (l >= vlo) {
            int b = min((int)((l - vlo) * scale), NB2 - 1);
            atomicAdd(&hist2[b], 1u);
        }
    }

    // wave -> block reduce, then ONE slot write per block (no contended atomics)
    #pragma unroll
    for (int off = 32; off; off >>= 1) {
        sp  += __shfl_down(sp,  off);
        spt += __shfl_down(spt, off);
        st  += __shfl_down(st,  off);
        sgt += __shfl_down(sgt, off);
        cnt += __shfl_down(cnt, off);
    }
    __shared__ float    rs[4][4];
    __shared__ unsigned rc[4];
    int w = threadIdx.x >> 6;
    if ((threadIdx.x & 63) == 0) {
        rs[w][0] = sp; rs[w][1] = spt; rs[w][2] = st; rs[w][3] = sgt; rc[w] = cnt;
    }
    __syncthreads();
    if (threadIdx.x == 0) {
        float a0 = 0, a1 = 0, a2 = 0, a3 = 0;
        unsigned c = 0;
        #pragma unroll
        for (int i = 0; i < 4; ++i) {
            a0 += rs[i][0]; a1 += rs[i][1]; a2 += rs[i][2]; a3 += rs[i][3]; c += rc[i];
        }
        q0[blockIdx.x] = a0; q1[blockIdx.x] = a1; q2[blockIdx.x] = a2;
        q3[blockIdx.x] = a3; qc[blockIdx.x] = c;
    }
}

// ---------- k3: reduce partials + resolve threshold bin + emit ----------
__global__ __launch_bounds__(1024) void final_kernel(
    const unsigned* __restrict__ hist2, const float* __restrict__ band,
    const float* __restrict__ q0, const float* __restrict__ q1,
    const float* __restrict__ q2, const float* __restrict__ q3,
    const unsigned* __restrict__ qc, int nblocks,
    float* __restrict__ out, long long k)
{
    __shared__ unsigned lh[NB2];        // 16 KB
    __shared__ double red[16][5];
    __shared__ double fin[5];

    for (int i = threadIdx.x; i < NB2; i += 1024) lh[i] = hist2[i];

    double a0 = 0, a1 = 0, a2 = 0, a3 = 0, a4 = 0;
    for (int i = threadIdx.x; i < nblocks; i += 1024) {
        a0 += (double)q0[i]; a1 += (double)q1[i]; a2 += (double)q2[i];
        a3 += (double)q3[i]; a4 += (double)qc[i];
    }
    #pragma unroll
    for (int off = 32; off; off >>= 1) {
        a0 += __shfl_down(a0, off); a1 += __shfl_down(a1, off);
        a2 += __shfl_down(a2, off); a3 += __shfl_down(a3, off);
        a4 += __shfl_down(a4, off);
    }
    int w = threadIdx.x >> 6;
    if ((threadIdx.x & 63) == 0) {
        red[w][0] = a0; red[w][1] = a1; red[w][2] = a2; red[w][3] = a3; red[w][4] = a4;
    }
    __syncthreads();
    if (threadIdx.x == 0) {
        double f0 = 0, f1 = 0, f2 = 0, f3 = 0, f4 = 0;
        for (int i = 0; i < 16; ++i) {
            f0 += red[i][0]; f1 += red[i][1]; f2 += red[i][2];
            f3 += red[i][3]; f4 += red[i][4];
        }
        fin[0] = f0; fin[1] = f1; fin[2] = f2; fin[3] = f3; fin[4] = f4;
    }
    __syncthreads();
    if (threadIdx.x >= 64) return;

    int lane = threadIdx.x;
    double SP = fin[0], SPT = fin[1], ST = fin[2], SGT = fin[3];
    long long CNT = (long long)fin[4];

    double vlo = (double)band[0], vhi = (double)band[1];
    double binw = (vhi - vlo) / NB2;
    long long k2 = k - CNT;

    int base = lane << 6;               // 64 bins per lane (LDS-resident)
    unsigned long long cchunk = 0;
    double wchunk = 0.0;
    for (int j = 0; j < 64; ++j) {
        unsigned h = lh[base + j];
        cchunk += h;
        wchunk += (double)h * (vlo + (base + j + 0.5) * binw);
    }
    unsigned long long cs = cchunk;
    double wsum = wchunk;
    #pragma unroll
    for (int off = 1; off < 64; off <<= 1) {
        unsigned long long cv = __shfl_down(cs, off);
        double wv = __shfl_down(wsum, off);
        if (lane + off < 64) { cs += cv; wsum += wv; }
    }
    unsigned long long total = __shfl(cs, 0);
    double wtotal = __shfl(wsum, 0);

    double I = SPT, U = SP + ST;
    double dice_part = 0.5 * (1.0 - (2.0 * I + 1e-6) / (U + 1e-6));

    if (k2 <= 0) {
        if (lane == 0) out[0] = (float)(SGT / (double)k + dice_part);
        return;
    }
    if ((unsigned long long)k2 > total) {
        if (lane == 0) {
            double sum_top = SGT + wtotal + (double)(k2 - (long long)total) * vlo;
            out[0] = (float)(sum_top / (double)k + dice_part);
        }
        return;
    }
    unsigned long long c = cs - cchunk;
    double wacc = wsum - wchunk;
    for (int j = 63; j >= 0; --j) {
        unsigned h = lh[base + j];
        double val = vlo + (base + j + 0.5) * binw;
        if (c < (unsigned long long)k2 && (unsigned long long)k2 <= c + h) {
            double sum_top = SGT + wacc + (double)((long long)k2 - (long long)c) * val;
            out[0] = (float)(sum_top / (double)k + dice_part);
        }
        c += h;
        wacc += (double)h * val;
    }
}

extern "C" void kernel_launch(void* const* d_in, const int* in_sizes, int n_in,
                              void* d_out, int out_size, void* d_ws, size_t ws_size,
                              hipStream_t stream)
{
    const float* x = (const float*)d_in[0];
    const float* t = (const float*)d_in[1];
    float* out = (float*)d_out;
    int n = in_sizes[0];
    int n4 = n >> 2;
    long long k = (long long)((double)n * 0.2);   // Python int() truncation
    if (k < 1) k = 1;

    long long S = (long long)(n4 >> 4) * 4;       // sampled element count
    long long ks = (S > 0) ? (long long)((double)k * (double)S / (double)n) : 0;
    long long M = 4096;                           // ~13 sigma sample-rank margin

    int tilesz = 256 * VEC;                       // float4 per tile
    int grid = (n4 + tilesz - 1) / tilesz;
    if (grid < 1) grid = 1;

    unsigned char* ws = (unsigned char*)d_ws;
    unsigned* H1    = (unsigned*)(ws);                 // 32 KB
    unsigned* hist2 = (unsigned*)(ws + 32768);         // 16 KB
    float*    band  = (float*)(ws + 49152);            // 8 B
    size_t po = 50176;                                 // partials base (256-aligned)
    size_t pstride = (((size_t)grid * 4) + 255) & ~(size_t)255;
    float*    q0 = (float*)(ws + po);
    float*    q1 = (float*)(ws + po + pstride);
    float*    q2 = (float*)(ws + po + 2 * pstride);
    float*    q3 = (float*)(ws + po + 3 * pstride);
    unsigned* qc = (unsigned*)(ws + po + 4 * pstride);

    hipMemsetAsync(d_ws, 0, 49152, stream);          // H1 + hist2 only

    sample_kernel<<<256, 256, 0, stream>>>((const float4*)x, (const float4*)t, H1, n4);
    band_kernel<<<1, 256, 0, stream>>>(H1, band, ks, M);
    main_kernel<<<grid, 256, 0, stream>>>((const float4*)x, (const float4*)t,
                                          band, hist2, q0, q1, q2, q3, qc, x, t, n, n4);
    final_kernel<<<1, 1024, 0, stream>>>(hist2, band, q0, q1, q2, q3, qc, grid, out, k);
}